// Round 5
// baseline (13283.885 us; speedup 1.0000x reference)
//
#include <hip/hip_runtime.h>
#include <math.h>

#define NB 4
#define NE 64
#define BE 256          // NB*NE
#define LAT 256
#define NC 512          // channels == window
#define NT 128          // n_frames
#define NDEF 65536      // NC*NT
#define NIMP 4096
#define NF 16           // impulse frames
#define EPSN 1e-8f
#define SPB 4           // sequences per scan block
#define NSCAN 64        // scan blocks (BE/SPB)

typedef unsigned short ushort8 __attribute__((ext_vector_type(8)));
typedef short short8v __attribute__((ext_vector_type(8)));
typedef float f32x4 __attribute__((ext_vector_type(4)));

__device__ __forceinline__ unsigned short f2bf(float f) {
  const unsigned u = __float_as_uint(f);
  return (unsigned short)((u + 0x7FFFu + ((u >> 16) & 1u)) >> 16);  // RNE
}

// ---------------------------------------------------------------------------
// single-barrier block reduction: 512 threads each contribute v[NR]; every
// thread gets the block sum in out[NR]. red is a flat >=8*NR float buffer.
// Caller must ensure no other use of `red` races (alternate buffers).
// ---------------------------------------------------------------------------
template <int NR>
__device__ __forceinline__ void blk_reduce1(const float* v, float* out,
                                            float* red) {
  const int tid = threadIdx.x, wave = tid >> 6, lane = tid & 63;
  float s[NR];
#pragma unroll
  for (int i = 0; i < NR; ++i) s[i] = v[i];
#pragma unroll
  for (int off = 32; off; off >>= 1) {
#pragma unroll
    for (int i = 0; i < NR; ++i) s[i] += __shfl_down(s[i], off);
  }
  if (lane == 0) {
#pragma unroll
    for (int i = 0; i < NR; ++i) red[wave * NR + i] = s[i];
  }
  __syncthreads();
#pragma unroll
  for (int i = 0; i < NR; ++i) {
    float a = 0.f;
#pragma unroll
    for (int w = 0; w < 8; ++w) a += red[w * NR + i];
    out[i] = a;
  }
}

// ---------------------------------------------------------------------------
// K0: swizzle Ws_lat (4 x [512 k][512 n] f32) into wave-linear MFMA B-frag
// order, bf16. Fragment (layer, wv, kt, p) lives at
//   Wmf[ ((layer*8+wv)*64 + kt*4 + p)*512 + lane*8 + j ]
//     = bf16( W[layer][kt*32 + (lane>>4)*8 + j][wv*64 + p*16 + (lane&15)] )
// so wave wv streams a CONTIGUOUS 64KB block per layer. grid 2048, block 64.
// ---------------------------------------------------------------------------
__global__ __launch_bounds__(64) void k_cvt(const float* __restrict__ W,
                                            unsigned short* __restrict__ Wmf) {
  const int lane = threadIdx.x;
  const int gg = blockIdx.x;
  const int p = gg & 3;
  const int kt = (gg >> 2) & 15;
  const int wv = (gg >> 6) & 7;
  const int layer = gg >> 9;
  const int col = wv * 64 + p * 16 + (lane & 15);
  const int k0 = kt * 32 + (lane >> 4) * 8;
  ushort8 o;
#pragma unroll
  for (int j = 0; j < 8; ++j)
    o[j] = f2bf(W[((size_t)layer * NC + k0 + j) * NC + col]);
  *reinterpret_cast<ushort8*>(Wmf + ((size_t)gg * 64 + lane) * 8) = o;
}

// ---------------------------------------------------------------------------
// K1: deform = embedding @ W_def + b_def      (256 x 256) @ (256 x 65536)
// ---------------------------------------------------------------------------
__global__ __launch_bounds__(256) void k_deform(
    const float* __restrict__ emb, const float* __restrict__ Wd,
    const float* __restrict__ bd, float* __restrict__ deform) {
  __shared__ float As[32][LAT];
  const int tid = threadIdx.x;
  const int c = blockIdx.x * 256 + tid;
  const int m0 = blockIdx.y * 32;
  for (int i = 0; i < 32; ++i) As[i][tid] = emb[(m0 + i) * LAT + tid];
  __syncthreads();
  float acc[32];
#pragma unroll
  for (int i = 0; i < 32; ++i) acc[i] = 0.f;
  for (int k = 0; k < LAT; k += 4) {
    const float w0 = Wd[(size_t)(k + 0) * NDEF + c];
    const float w1 = Wd[(size_t)(k + 1) * NDEF + c];
    const float w2 = Wd[(size_t)(k + 2) * NDEF + c];
    const float w3 = Wd[(size_t)(k + 3) * NDEF + c];
#pragma unroll
    for (int i = 0; i < 32; ++i) {
      const float4 a = *reinterpret_cast<const float4*>(&As[i][k]);
      acc[i] = fmaf(a.x, w0, acc[i]);
      acc[i] = fmaf(a.y, w1, acc[i]);
      acc[i] = fmaf(a.z, w2, acc[i]);
      acc[i] = fmaf(a.w, w3, acc[i]);
    }
  }
  const float bv = bd[c];
  for (int i = 0; i < 32; ++i)
    deform[(size_t)(m0 + i) * NDEF + c] = acc[i] + bv;
}

// ---------------------------------------------------------------------------
// K2: per-(be,t) rows of deform: unit_norm over channel dim, then
//   weights = x @ W_w + b_w ; biases = x @ W_b + b_b ; leak = sigmoid path.
// ---------------------------------------------------------------------------
__global__ __launch_bounds__(512) void k_wb(
    const float* __restrict__ deform, const float* __restrict__ Ww,
    const float* __restrict__ bw, const float* __restrict__ Wb,
    const float* __restrict__ bb, const float* __restrict__ Wl,
    const float* __restrict__ bl, float* __restrict__ weights,
    float* __restrict__ biases, float* __restrict__ leak) {
  __shared__ float xs[16][NC];
  __shared__ float rno[16], lks[16];
  const int tid = threadIdx.x;
  const int wave = tid >> 6, lane = tid & 63;
  const int be = blockIdx.x >> 3;
  const int t0 = (blockIdx.x & 7) * 16;
  const float* dbase = deform + (size_t)be * NDEF;
  for (int i = 0; i < 16; ++i)
    xs[i][tid] = dbase[(size_t)tid * NT + t0 + i];
  __syncthreads();
  for (int f = wave; f < 16; f += 8) {
    float s = 0.f;
#pragma unroll
    for (int j = 0; j < 8; ++j) {
      const float v = xs[f][lane + 64 * j];
      s = fmaf(v, v, s);
    }
#pragma unroll
    for (int off = 32; off; off >>= 1) s += __shfl_down(s, off);
    if (lane == 0) rno[f] = sqrtf(s);
  }
  __syncthreads();
#pragma unroll
  for (int i = 0; i < 16; ++i) xs[i][tid] = xs[i][tid] / (rno[i] + EPSN);
  __syncthreads();
  for (int f = wave; f < 16; f += 8) {
    float s = 0.f;
#pragma unroll
    for (int j = 0; j < 8; ++j)
      s = fmaf(xs[f][lane + 64 * j], Wl[lane + 64 * j], s);
#pragma unroll
    for (int off = 32; off; off >>= 1) s += __shfl_down(s, off);
    if (lane == 0) lks[f] = s;
  }
  __syncthreads();
  if (tid < 16) {
    const float v = lks[tid] + bl[0];
    leak[(size_t)be * NT + t0 + tid] = 0.1f + 0.98f / (1.f + expf(-v));
  }
  float accw[16], accb[16];
#pragma unroll
  for (int i = 0; i < 16; ++i) { accw[i] = 0.f; accb[i] = 0.f; }
  for (int k = 0; k < NC; k += 2) {
    const float w0 = Ww[(size_t)k * NC + tid];
    const float w1 = Ww[(size_t)(k + 1) * NC + tid];
    const float v0 = Wb[(size_t)k * NC + tid];
    const float v1 = Wb[(size_t)(k + 1) * NC + tid];
#pragma unroll
    for (int i = 0; i < 16; ++i) {
      const float2 a = *reinterpret_cast<const float2*>(&xs[i][k]);
      accw[i] = fmaf(a.x, w0, accw[i]);
      accw[i] = fmaf(a.y, w1, accw[i]);
      accb[i] = fmaf(a.x, v0, accb[i]);
      accb[i] = fmaf(a.y, v1, accb[i]);
    }
  }
  const float bwv = bw[tid], bbv = bb[tid];
  for (int i = 0; i < 16; ++i) {
    const size_t o = ((size_t)be * NT + t0 + i) * NC + tid;
    weights[o] = accw[i] + bwv;
    biases[o] = accb[i] + bbv;
  }
}

// ---------------------------------------------------------------------------
// 16-row tile x (512x512) GEMM helper: xs[16][512] in LDS, thread = column.
// ---------------------------------------------------------------------------
__device__ __forceinline__ void tile_gemm16(const float (*xs)[NC],
                                            const float* __restrict__ W,
                                            int tid, float acc[16]) {
#pragma unroll
  for (int i = 0; i < 16; ++i) acc[i] = 0.f;
  for (int k = 0; k < NC; k += 4) {
    const float w0 = W[(size_t)(k + 0) * NC + tid];
    const float w1 = W[(size_t)(k + 1) * NC + tid];
    const float w2 = W[(size_t)(k + 2) * NC + tid];
    const float w3 = W[(size_t)(k + 3) * NC + tid];
#pragma unroll
    for (int i = 0; i < 16; ++i) {
      const float4 a = *reinterpret_cast<const float4*>(&xs[i][k]);
      acc[i] = fmaf(a.x, w0, acc[i]);
      acc[i] = fmaf(a.y, w1, acc[i]);
      acc[i] = fmaf(a.z, w2, acc[i]);
      acc[i] = fmaf(a.w, w3, acc[i]);
    }
  }
}

// LN (+leaky) stats applied in-place on xs[16][NC]
__device__ __forceinline__ void ln_leaky16(float (*xs)[NC],
                                           const float* __restrict__ g,
                                           const float* __restrict__ bt,
                                           int layer, int tid, float* mu_s,
                                           float* rs_s) {
  const int wave = tid >> 6, lane = tid & 63;
  for (int f = wave; f < 16; f += 8) {
    float s = 0.f, s2 = 0.f;
#pragma unroll
    for (int j = 0; j < 8; ++j) {
      const float v = xs[f][lane + 64 * j];
      s += v;
      s2 = fmaf(v, v, s2);
    }
#pragma unroll
    for (int off = 32; off; off >>= 1) {
      s += __shfl_down(s, off);
      s2 += __shfl_down(s2, off);
    }
    if (lane == 0) {
      const float mu = s * (1.f / NC);
      mu_s[f] = mu;
      rs_s[f] = rsqrtf(s2 * (1.f / NC) - mu * mu + 1e-5f);
    }
  }
  __syncthreads();
  const float gv = g[layer * NC + tid], btv = bt[layer * NC + tid];
#pragma unroll
  for (int i = 0; i < 16; ++i) {
    const float y = (xs[i][tid] - mu_s[i]) * rs_s[i] * gv + btv;
    xs[i][tid] = y > 0.f ? y : 0.2f * y;
  }
  __syncthreads();
}

// ---------------------------------------------------------------------------
// K3: windowed impulse -> mlp_imp -> unit_norm * window-norm -> emb stream.
// ---------------------------------------------------------------------------
__global__ __launch_bounds__(512) void k_imp(
    const float* __restrict__ impulse, const float* __restrict__ Ws,
    const float* __restrict__ bs, const float* __restrict__ g,
    const float* __restrict__ bt, float* __restrict__ embo) {
  __shared__ float xs[16][NC];
  __shared__ float wno[16], mu_s[16], rs_s[16], ono[16];
  const int tid = threadIdx.x;
  const int wave = tid >> 6, lane = tid & 63;
  const int be = blockIdx.x;
  const float* ib = impulse + (size_t)be * NIMP;
  for (int f = 0; f < 16; ++f) {
    const int s = f * 256 + tid;
    xs[f][tid] = (s < NIMP) ? ib[s] : 0.f;
  }
  __syncthreads();
  for (int f = wave; f < 16; f += 8) {
    float s = 0.f;
#pragma unroll
    for (int j = 0; j < 8; ++j) {
      const float v = xs[f][lane + 64 * j];
      s = fmaf(v, v, s);
    }
#pragma unroll
    for (int off = 32; off; off >>= 1) s += __shfl_down(s, off);
    if (lane == 0) wno[f] = sqrtf(s);
  }
  __syncthreads();
  float acc[16];
  for (int layer = 0; layer < 4; ++layer) {
    tile_gemm16(xs, Ws + (size_t)layer * NC * NC, tid, acc);
    __syncthreads();
    const float bv = bs[layer * NC + tid];
#pragma unroll
    for (int i = 0; i < 16; ++i) xs[i][tid] = acc[i] + bv;
    __syncthreads();
    if (layer < 3) ln_leaky16(xs, g, bt, layer, tid, mu_s, rs_s);
  }
  for (int f = wave; f < 16; f += 8) {
    float s = 0.f;
#pragma unroll
    for (int j = 0; j < 8; ++j) {
      const float v = xs[f][lane + 64 * j];
      s = fmaf(v, v, s);
    }
#pragma unroll
    for (int off = 32; off; off >>= 1) s += __shfl_down(s, off);
    if (lane == 0) ono[f] = sqrtf(s);
  }
  __syncthreads();
  for (int f = 0; f < 16; ++f)
    embo[((size_t)be * NF + f) * NC + tid] =
        xs[f][tid] / (ono[f] + EPSN) * wno[f];
}

// ---------------------------------------------------------------------------
// K4 helper: 16x512x512 bf16 MFMA GEMM for one layer slice of one wave.
// wl = wave's contiguous 64KB weight block; A in LDS (rows 0..3 live,
// 4..15 zero). 2-deep register double-buffer on B-frags and A-frags.
// ---------------------------------------------------------------------------
__device__ __forceinline__ void scan_gemm(f32x4 acc[4],
                                          const unsigned short* __restrict__ wl,
                                          const unsigned short* A_lds,
                                          int abase, int akoff, int axor) {
  const char* ab = (const char*)A_lds;
#define LDA_(KT) \
  (*(const short8v*)(ab + abase + ((((KT)*64) + akoff) ^ axor)))
  short8v b0[4], b1[4], a0, a1;
#pragma unroll
  for (int p = 0; p < 4; ++p)
    b0[p] = *(const short8v*)(wl + p * 512);
  a0 = LDA_(0);
#pragma unroll
  for (int p = 0; p < 4; ++p)
    b1[p] = *(const short8v*)(wl + 2048 + p * 512);
  a1 = LDA_(1);
#pragma unroll
  for (int kt = 0; kt < 16; ++kt) {
    if ((kt & 1) == 0) {
#pragma unroll
      for (int p = 0; p < 4; ++p)
        acc[p] = __builtin_amdgcn_mfma_f32_16x16x32_bf16(a0, b0[p], acc[p],
                                                         0, 0, 0);
      if (kt + 2 < 16) {
#pragma unroll
        for (int p = 0; p < 4; ++p)
          b0[p] = *(const short8v*)(wl + (kt + 2) * 2048 + p * 512);
        a0 = LDA_(kt + 2);
      }
    } else {
#pragma unroll
      for (int p = 0; p < 4; ++p)
        acc[p] = __builtin_amdgcn_mfma_f32_16x16x32_bf16(a1, b1[p], acc[p],
                                                         0, 0, 0);
      if (kt + 2 < 16) {
#pragma unroll
        for (int p = 0; p < 4; ++p)
          b1[p] = *(const short8v*)(wl + (kt + 2) * 2048 + p * 512);
        a1 = LDA_(kt + 2);
      }
    }
  }
#undef LDA_
}

// ---------------------------------------------------------------------------
// K4: the sequential scan, MFMA v3.
// 64 blocks x 512 threads; 4 seqs/block (rows 4..15 of the M=16 tile zero).
// Wave w owns output cols [w*64, w*64+64). Weights streamed wave-linear from
// Wmf; weights/biases/embw prefetched one t ahead; leak staged in LDS;
// cn carried across steps (cn' = |cn-on|) when no impulse is added.
// ---------------------------------------------------------------------------
__global__ __launch_bounds__(512) void k_scan(
    const float* __restrict__ weights, const float* __restrict__ biases,
    const float* __restrict__ leak, const float* __restrict__ embw,
    const unsigned short* __restrict__ Wmf, const float* __restrict__ bs,
    const float* __restrict__ g, const float* __restrict__ bt,
    float* __restrict__ olb, float* __restrict__ onb) {
  __shared__ __align__(16) unsigned short A_lds[16 * NC];  // 16KB
  __shared__ float ol_lds[SPB][NC];                        // 8KB
  __shared__ float redA[64];
  __shared__ float redB[32];
  __shared__ float st1[8][SPB], st2[8][SPB];
  __shared__ float lk_lds[SPB][NT];

  const int tid = threadIdx.x;
  const int wave = tid >> 6, lane = tid & 63;
  const int seq0 = blockIdx.x * SPB;

  // stage leak slice (one element per thread)
  {
    const int r = tid >> 7, tt = tid & 127;
    lk_lds[r][tt] = leak[(size_t)(seq0 + r) * NT + tt];
  }
  // zero the pad rows 4..15 of A (never written again)
  {
    unsigned* z = (unsigned*)(A_lds + SPB * NC);
    for (int i = tid; i < (16 - SPB) * NC / 2; i += 512) z[i] = 0u;
  }

  // per-lane MFMA geometry
  const int arow = lane & 15;
  const int kgrp = lane >> 4;
  const int abase = arow * (NC * 2);
  const int axor = (arow & 7) << 4;
  const int akoff = kgrp * 16;
  const bool crow = (kgrp == 0);  // lanes holding C rows 0..3

  // hoist per-lane (t-invariant) bias / LN params for this wave's 4 n-tiles
  float bsv[4][4], gv[3][4], btv[3][4];
#pragma unroll
  for (int p = 0; p < 4; ++p) {
    const int cp = wave * 64 + p * 16 + (lane & 15);
#pragma unroll
    for (int l = 0; l < 4; ++l) bsv[l][p] = bs[l * NC + cp];
#pragma unroll
    for (int l = 0; l < 3; ++l) {
      gv[l][p] = g[l * NC + cp];
      btv[l][p] = bt[l * NC + cp];
    }
  }

  // initial prefetch for t=0
  float wpre[SPB], bpre[SPB], epre[SPB];
#pragma unroll
  for (int r = 0; r < SPB; ++r) {
    const size_t o = ((size_t)(seq0 + r) * NT) * NC + tid;
    wpre[r] = weights[o];
    bpre[r] = biases[o];
    epre[r] = embw[((size_t)(seq0 + r) * NF) * NC + tid];
  }

  __syncthreads();

  float h[SPB], cn[SPB];
#pragma unroll
  for (int r = 0; r < SPB; ++r) { h[r] = 0.f; cn[r] = 0.f; }

#pragma unroll 1
  for (int t = 0; t < NT; ++t) {
    float hw[SPB];
    if (t < NF) {
#pragma unroll
      for (int r = 0; r < SPB; ++r) h[r] += epre[r];
      if (t + 1 < NF) {
#pragma unroll
        for (int r = 0; r < SPB; ++r)
          epre[r] = embw[((size_t)(seq0 + r) * NF + t + 1) * NC + tid];
      }
      float v8[8], s8[8];
#pragma unroll
      for (int r = 0; r < SPB; ++r) {
        hw[r] = fmaf(h[r], wpre[r], bpre[r]);
        v8[r] = h[r] * h[r];
        v8[SPB + r] = hw[r] * hw[r];
      }
      blk_reduce1<8>(v8, s8, redA);
#pragma unroll
      for (int r = 0; r < SPB; ++r) {
        cn[r] = sqrtf(s8[r]);
        h[r] = hw[r] * (cn[r] / (sqrtf(s8[SPB + r]) + EPSN));
      }
    } else {
      float v4[SPB], s4[SPB];
#pragma unroll
      for (int r = 0; r < SPB; ++r) {
        hw[r] = fmaf(h[r], wpre[r], bpre[r]);
        v4[r] = hw[r] * hw[r];
      }
      blk_reduce1<SPB>(v4, s4, redA);
#pragma unroll
      for (int r = 0; r < SPB; ++r)
        h[r] = hw[r] * (cn[r] / (sqrtf(s4[r]) + EPSN));
    }
    // prefetch weights/biases for t+1 (overlaps the MFMA phase)
    if (t + 1 < NT) {
#pragma unroll
      for (int r = 0; r < SPB; ++r) {
        const size_t o = ((size_t)(seq0 + r) * NT + t + 1) * NC + tid;
        wpre[r] = weights[o];
        bpre[r] = biases[o];
      }
    }
    // pack x -> A rows 0..3 (bf16, swizzled)
    {
      char* ab = (char*)A_lds;
#pragma unroll
      for (int r = 0; r < SPB; ++r)
        *(unsigned short*)(ab + r * 1024 + ((tid * 2) ^ ((r & 7) << 4))) =
            f2bf(h[r]);
    }
    __syncthreads();

    // ---- 3 hidden layers ----
#pragma unroll
    for (int layer = 0; layer < 3; ++layer) {
      f32x4 acc[4];
#pragma unroll
      for (int p = 0; p < 4; ++p) acc[p] = (f32x4){0.f, 0.f, 0.f, 0.f};
      scan_gemm(acc, Wmf + (size_t)(layer * 8 + wave) * 32768 + lane * 8,
                A_lds, abase, akoff, axor);
      float s1[SPB], s2[SPB];
#pragma unroll
      for (int q = 0; q < SPB; ++q) { s1[q] = 0.f; s2[q] = 0.f; }
#pragma unroll
      for (int p = 0; p < 4; ++p) {
#pragma unroll
        for (int q = 0; q < SPB; ++q) {
          const float y = acc[p][q] + bsv[layer][p];
          acc[p][q] = y;
          s1[q] += y;
          s2[q] = fmaf(y, y, s2[q]);
        }
      }
#pragma unroll
      for (int off = 1; off < 16; off <<= 1) {
#pragma unroll
        for (int q = 0; q < SPB; ++q) {
          s1[q] += __shfl_xor(s1[q], off);
          s2[q] += __shfl_xor(s2[q], off);
        }
      }
      if (lane == 0) {
#pragma unroll
        for (int q = 0; q < SPB; ++q) {
          st1[wave][q] = s1[q];
          st2[wave][q] = s2[q];
        }
      }
      __syncthreads();
      float mu[SPB], rs[SPB];
#pragma unroll
      for (int q = 0; q < SPB; ++q) {
        float a1 = 0.f, a2 = 0.f;
#pragma unroll
        for (int w = 0; w < 8; ++w) {
          a1 += st1[w][q];
          a2 += st2[w][q];
        }
        mu[q] = a1 * (1.f / NC);
        rs[q] = rsqrtf(a2 * (1.f / NC) - mu[q] * mu[q] + 1e-5f);
      }
      if (crow) {
        char* ab = (char*)A_lds;
#pragma unroll
        for (int q = 0; q < SPB; ++q) {
#pragma unroll
          for (int p = 0; p < 4; ++p) {
            float y = (acc[p][q] - mu[q]) * rs[q] * gv[layer][p] +
                      btv[layer][p];
            y = y > 0.f ? y : 0.2f * y;
            const int cp = wave * 64 + p * 16 + (lane & 15);
            *(unsigned short*)(ab + q * 1024 +
                               ((cp * 2) ^ ((q & 7) << 4))) = f2bf(y);
          }
        }
      }
      __syncthreads();
    }

    // ---- final linear -> ol; epilogue ----
    {
      f32x4 acc[4];
#pragma unroll
      for (int p = 0; p < 4; ++p) acc[p] = (f32x4){0.f, 0.f, 0.f, 0.f};
      scan_gemm(acc, Wmf + (size_t)(3 * 8 + wave) * 32768 + lane * 8, A_lds,
                abase, akoff, axor);
      float s2[SPB];
#pragma unroll
      for (int q = 0; q < SPB; ++q) s2[q] = 0.f;
#pragma unroll
      for (int p = 0; p < 4; ++p) {
#pragma unroll
        for (int q = 0; q < SPB; ++q) {
          const float y = acc[p][q] + bsv[3][p];
          acc[p][q] = y;
          s2[q] = fmaf(y, y, s2[q]);
        }
      }
#pragma unroll
      for (int off = 1; off < 16; off <<= 1) {
#pragma unroll
        for (int q = 0; q < SPB; ++q) s2[q] += __shfl_xor(s2[q], off);
      }
      if (lane == 0) {
#pragma unroll
        for (int q = 0; q < SPB; ++q) st2[wave][q] = s2[q];
      }
      if (crow) {
#pragma unroll
        for (int q = 0; q < SPB; ++q) {
#pragma unroll
          for (int p = 0; p < 4; ++p)
            ol_lds[q][wave * 64 + p * 16 + (lane & 15)] = acc[p][q];
        }
      }
      __syncthreads();
      float sc[SPB], on[SPB];
#pragma unroll
      for (int r = 0; r < SPB; ++r) {
        float a2 = 0.f;
#pragma unroll
        for (int w = 0; w < 8; ++w) a2 += st2[w][r];
        const float no = sqrtf(a2);
        sc[r] = cn[r] * lk_lds[r][t] / (no + EPSN);
        on[r] = no * sc[r];
      }
      if (tid < SPB) onb[(size_t)(seq0 + tid) * NT + t] = on[tid];
      float v4[SPB], s4[SPB];
#pragma unroll
      for (int r = 0; r < SPB; ++r) {
        const float olv = ol_lds[r][tid] * sc[r];
        olb[((size_t)(seq0 + r) * NT + t) * NC + tid] = olv;
        h[r] -= olv;
        v4[r] = h[r] * h[r];
      }
      blk_reduce1<SPB>(v4, s4, redB);
#pragma unroll
      for (int r = 0; r < SPB; ++r) {
        h[r] *= (cn[r] - on[r]) / (sqrtf(s4[r]) + EPSN);
        cn[r] = fabsf(cn[r] - on[r]);  // ||h|| carried exactly
      }
    }
  }
}

// ---------------------------------------------------------------------------
// K5: batched out-MLP on all 32768 ol rows: of = unit_norm(mlp_out(ol)*ham)*on
// ---------------------------------------------------------------------------
__global__ __launch_bounds__(512) void k_out(
    const float* __restrict__ olb, const float* __restrict__ onb,
    const float* __restrict__ Ws, const float* __restrict__ bs,
    const float* __restrict__ g, const float* __restrict__ bt,
    float* __restrict__ ofb) {
  __shared__ float xs[16][NC];
  __shared__ float mu_s[16], rs_s[16], ono[16];
  const int tid = threadIdx.x;
  const int wave = tid >> 6, lane = tid & 63;
  const int m0 = blockIdx.x * 16;
  for (int i = 0; i < 16; ++i)
    xs[i][tid] = olb[(size_t)(m0 + i) * NC + tid];
  __syncthreads();
  float acc[16];
  for (int layer = 0; layer < 4; ++layer) {
    tile_gemm16(xs, Ws + (size_t)layer * NC * NC, tid, acc);
    __syncthreads();
    const float bv = bs[layer * NC + tid];
#pragma unroll
    for (int i = 0; i < 16; ++i) xs[i][tid] = acc[i] + bv;
    __syncthreads();
    if (layer < 3) ln_leaky16(xs, g, bt, layer, tid, mu_s, rs_s);
  }
  const float ham =
      0.54f - 0.46f * cosf(6.283185307179586f * (float)tid / (float)NC);
#pragma unroll
  for (int i = 0; i < 16; ++i) xs[i][tid] *= ham;
  __syncthreads();
  for (int f = wave; f < 16; f += 8) {
    float s = 0.f;
#pragma unroll
    for (int j = 0; j < 8; ++j) {
      const float vv = xs[f][lane + 64 * j];
      s = fmaf(vv, vv, s);
    }
#pragma unroll
    for (int off = 32; off; off >>= 1) s += __shfl_down(s, off);
    if (lane == 0) ono[f] = sqrtf(s);
  }
  __syncthreads();
  for (int i = 0; i < 16; ++i) {
    const float onv = onb[m0 + i];
    ofb[(size_t)(m0 + i) * NC + tid] = xs[i][tid] / (ono[i] + EPSN) * onv;
  }
}

// ---------------------------------------------------------------------------
// K6: overlap-add at hop 256, trim to 32768.
// ---------------------------------------------------------------------------
__global__ __launch_bounds__(256) void k_oa(const float* __restrict__ ofb,
                                            float* __restrict__ out) {
  const int idx = blockIdx.x * 256 + threadIdx.x;
  if (idx >= BE * 32768) return;
  const int be = idx >> 15;
  const int s = idx & 32767;
  const int t1 = s >> 8;
  float v = ofb[((size_t)be * NT + t1) * NC + (s - (t1 << 8))];
  if (t1 >= 1)
    v += ofb[((size_t)be * NT + (t1 - 1)) * NC + (s - ((t1 - 1) << 8))];
  out[idx] = v;
}

// ---------------------------------------------------------------------------
// Workspace (< 256 MiB): region A (deform->olb) 64 MiB, region B
// (weights->ofb) 64 MiB, region C (biases) 64 MiB, small buffers ~12 MiB.
// ---------------------------------------------------------------------------
extern "C" void kernel_launch(void* const* d_in, const int* in_sizes, int n_in,
                              void* d_out, int out_size, void* d_ws,
                              size_t ws_size, hipStream_t stream) {
  const float* embedding = (const float*)d_in[0];
  const float* impulse = (const float*)d_in[1];
  const float* W_def = (const float*)d_in[2];
  const float* b_def = (const float*)d_in[3];
  const float* W_w = (const float*)d_in[4];
  const float* b_w = (const float*)d_in[5];
  const float* W_b = (const float*)d_in[6];
  const float* b_b = (const float*)d_in[7];
  const float* W_l = (const float*)d_in[8];
  const float* b_l = (const float*)d_in[9];
  const float* Ws_imp = (const float*)d_in[10];
  const float* bs_imp = (const float*)d_in[11];
  const float* g_imp = (const float*)d_in[12];
  const float* bt_imp = (const float*)d_in[13];
  const float* Ws_lat = (const float*)d_in[14];
  const float* bs_lat = (const float*)d_in[15];
  const float* g_lat = (const float*)d_in[16];
  const float* bt_lat = (const float*)d_in[17];
  const float* Ws_out = (const float*)d_in[18];
  const float* bs_out = (const float*)d_in[19];
  const float* g_out = (const float*)d_in[20];
  const float* bt_out = (const float*)d_in[21];
  float* out = (float*)d_out;

  float* ws = (float*)d_ws;
  float* deform = ws;                  // region A (reused as olb)
  float* weights = deform + 16777216;  // region B (reused as ofb)
  float* biases = weights + 16777216;  // region C
  float* leakb = biases + 16777216;    // 32,768 f
  float* embw = leakb + 32768;         // 2,097,152 f
  float* onb = embw + 2097152;         // 32,768 f
  unsigned short* wmf = (unsigned short*)(onb + 32768);  // 2,097,152 us
  float* olb = deform;                 // alias: deform dead after k_wb
  float* ofb = weights;                // alias: weights dead after k_scan

  k_cvt<<<2048, 64, 0, stream>>>(Ws_lat, wmf);
  k_deform<<<dim3(256, 8), 256, 0, stream>>>(embedding, W_def, b_def, deform);
  k_wb<<<2048, 512, 0, stream>>>(deform, W_w, b_w, W_b, b_b, W_l, b_l,
                                 weights, biases, leakb);
  k_imp<<<256, 512, 0, stream>>>(impulse, Ws_imp, bs_imp, g_imp, bt_imp, embw);
  k_scan<<<NSCAN, 512, 0, stream>>>(weights, biases, leakb, embw, wmf, bs_lat,
                                    g_lat, bt_lat, olb, onb);
  k_out<<<2048, 512, 0, stream>>>(olb, onb, Ws_out, bs_out, g_out, bt_out,
                                  ofb);
  k_oa<<<32768, 256, 0, stream>>>(ofb, out);
}